// Round 10
// baseline (138.628 us; speedup 1.0000x reference)
//
#include <hip/hip_runtime.h>
#include <hip/hip_fp16.h>
#include <math.h>

#define NN 50000
#define NE 800000
#define FIN 256
#define FOUT 64
#define HEADS 4
#define HF 256   // HEADS*FOUT
#define CAP 64   // padded slots per node; P(deg>64 | Poisson(16)) ~ 1e-19/node
#define CSTRIDE 16   // cnt padded: 1 counter per 64B line

typedef unsigned short u16;
typedef unsigned int u32;
typedef __attribute__((ext_vector_type(4))) u16 u16x4;
typedef __attribute__((ext_vector_type(8))) u16 u16x8;
typedef __attribute__((ext_vector_type(8))) short short8;
typedef __attribute__((ext_vector_type(4))) float f32x4;

__device__ __forceinline__ u16 f2bf(float x) {
  u32 u = __float_as_uint(x);
  u += 0x7fffu + ((u >> 16) & 1u);          // RNE
  return (u16)(u >> 16);
}
__device__ __forceinline__ float bf2f(u16 u) {
  return __uint_as_float(((u32)u) << 16);
}
__device__ __forceinline__ void gload_lds16(u16* lds, const u16* g) {
  __builtin_amdgcn_global_load_lds(
      (const __attribute__((address_space(1))) u32*)g,
      (__attribute__((address_space(3))) u32*)lds, 16, 0, 0);
}

// ---------------- K0: tiny pre: make Bt + zero padded cnt -------------------
#define BT_B   256
#define ZERO_B 782   // 50000*16 ints = 200000 int4 / 256
__global__ __launch_bounds__(256) void tiny_pre_k(const float* __restrict__ W,
                                                  u16* __restrict__ Bt,
                                                  int* __restrict__ cnt) {
  const int b = blockIdx.x, tid = threadIdx.x;
  if (b < BT_B) {
    int t = b * 256 + tid;                   // 65536 exactly
    int ho = t >> 8, f = t & 255;
    int h = ho >> 6, o = ho & 63;
    Bt[t] = f2bf(W[h * (FIN * FOUT) + f * FOUT + o]);
  } else {
    int i = (b - BT_B) * 256 + tid;          // int4 index
    if (i < (NN * CSTRIDE) / 4) {
      int4 z = { 0, 0, 0, 0 };
      ((int4*)cnt)[i] = z;
    }
  }
}

// ---------------- K1: FUSED  gemm(+logits)  ||  scatter ---------------------
// blocks [0, GEMM_B): 128x256 MFMA GEMM; blocks [GEMM_B, +SCAT_B): edge scatter.
#define GEMM_B 391                 // ceil(NN/128)
#define SCAT_B 1563                // ceil(NE/512)
__global__ __launch_bounds__(512) void gemm_scat_k(const float* __restrict__ X,
                                                   const u16* __restrict__ Bt,
                                                   u16* __restrict__ C,
                                                   const float* __restrict__ a_self,
                                                   const float* __restrict__ a_neigh,
                                                   float* __restrict__ sself,
                                                   float* __restrict__ sneigh,
                                                   const int* __restrict__ erow,
                                                   const int* __restrict__ ecol,
                                                   const float* __restrict__ adj,
                                                   int* __restrict__ cnt,
                                                   u32* __restrict__ slots,
                                                   int M) {
  __shared__ __align__(16) u16 smA[128 * 64];
  __shared__ __align__(16) u16 smB[256 * 64];
  const int tid = threadIdx.x;

  if (blockIdx.x >= GEMM_B) {
    // ---------------- scatter part ----------------
    int e = (blockIdx.x - GEMM_B) * 512 + tid;
    if (e < NE) {
      int r = erow[e];
      int c = ecol[e];
      float av = adj[e];
      __half ha = __float2half_rn(av);
      u32 rec = (u32)c | ((u32)(*(u16*)&ha) << 16);
      int p = atomicAdd(&cnt[r * CSTRIDE], 1);   // padded: 1 counter / 64B line
      if (p < CAP)
        __builtin_nontemporal_store(rec, &slots[r * CAP + p]);  // no RFO
    }
    return;
  }

  // ---------------- gemm part ----------------
  const int m0 = blockIdx.x * 128;
  const int lane = tid & 63, wid = tid >> 6;
  const int wr = wid >> 2, wc = wid & 3;
  const int arow = tid >> 3;                  // 0..63
  const int acol = (tid & 7) * 8;             // 0..56 step 8
  f32x4 acc[4][4] = {};

  for (int k0 = 0; k0 < FIN; k0 += 64) {
    float4 p[2][2];
#pragma unroll
    for (int c = 0; c < 2; ++c) {
      int row = m0 + c * 64 + arow;
      if (row > M - 1) row = M - 1;
      const float* ap = X + (size_t)row * 256 + k0 + acol;
      p[c][0] = *(const float4*)ap;
      p[c][1] = *(const float4*)(ap + 4);
    }
#pragma unroll
    for (int c = 0; c < 4; ++c) {
      int row = c * 64 + arow;
      gload_lds16(&smB[(c * 64 + arow) * 64 + acol], Bt + row * 256 + k0 + acol);
    }
#pragma unroll
    for (int c = 0; c < 2; ++c) {
      u16x8 av = { f2bf(p[c][0].x), f2bf(p[c][0].y), f2bf(p[c][0].z), f2bf(p[c][0].w),
                   f2bf(p[c][1].x), f2bf(p[c][1].y), f2bf(p[c][1].z), f2bf(p[c][1].w) };
      *(u16x8*)&smA[(c * 64 + arow) * 64 + acol] = av;
    }
    asm volatile("s_waitcnt vmcnt(0)" ::: "memory");
    __syncthreads();
#pragma unroll
    for (int kk = 0; kk < 2; ++kk) {
      const int kb = kk * 32 + (lane >> 4) * 8;
      short8 aF[4], bF[4];
#pragma unroll
      for (int mi = 0; mi < 4; ++mi)
        aF[mi] = *(const short8*)&smA[(wr * 64 + mi * 16 + (lane & 15)) * 64 + kb];
#pragma unroll
      for (int ni = 0; ni < 4; ++ni)
        bF[ni] = *(const short8*)&smB[(wc * 64 + ni * 16 + (lane & 15)) * 64 + kb];
#pragma unroll
      for (int mi = 0; mi < 4; ++mi)
#pragma unroll
        for (int ni = 0; ni < 4; ++ni)
          acc[mi][ni] = __builtin_amdgcn_mfma_f32_16x16x32_bf16(aF[mi], bF[ni], acc[mi][ni], 0, 0, 0);
    }
    __syncthreads();
  }
#pragma unroll
  for (int mi = 0; mi < 4; ++mi) {
#pragma unroll
    for (int ni = 0; ni < 4; ++ni) {
      f32x4 a = acc[mi][ni];
      int col = wc * 64 + ni * 16 + (lane & 15);
#pragma unroll
      for (int r = 0; r < 4; ++r) {
        int row = m0 + wr * 64 + mi * 16 + (lane >> 4) * 4 + r;
        if (row < M) C[(size_t)row * 256 + col] = f2bf(a[r]);
      }
    }
  }
  float asv[4], anv[4];
#pragma unroll
  for (int ni = 0; ni < 4; ++ni) {
    int col = wc * 64 + ni * 16 + (lane & 15);
    asv[ni] = a_self[col];
    anv[ni] = a_neigh[col];
  }
#pragma unroll
  for (int mi = 0; mi < 4; ++mi) {
#pragma unroll
    for (int r = 0; r < 4; ++r) {
      float ds = 0.f, dn = 0.f;
#pragma unroll
      for (int ni = 0; ni < 4; ++ni) {
        float v = acc[mi][ni][r];
        ds = fmaf(v, asv[ni], ds);
        dn = fmaf(v, anv[ni], dn);
      }
#pragma unroll
      for (int off = 1; off < 16; off <<= 1) {
        ds += __shfl_xor(ds, off, 64);
        dn += __shfl_xor(dn, off, 64);
      }
      if ((lane & 15) == 0) {
        int row = m0 + wr * 64 + mi * 16 + (lane >> 4) * 4 + r;
        if (row < M) {
          sself[row * 4 + wc] = ds;
          sneigh[row * 4 + wc] = dn;
        }
      }
    }
  }
}

// ---------------- K2: per-node weights + aggregate + bias + relu ------------
#define NODE_B 3125   // 3125 blocks x 8 half-waves = 25000; x2 nodes = NN
__global__ __launch_bounds__(256) void node8_k(const int* __restrict__ cnt,
                                               const u32* __restrict__ slots,
                                               const float4* __restrict__ sself4,
                                               const float4* __restrict__ sneigh4,
                                               const u16* __restrict__ fb,
                                               const float* __restrict__ bias,
                                               float* __restrict__ out) {
  const int tid = threadIdx.x;
  const int l = tid & 31;
  const int hsel = l >> 4;
  const int hw0 = blockIdx.x * 8 + (tid >> 5);   // 0..24999
  const float4 b0 = ((const float4*)bias)[l];
  const float4 b1 = ((const float4*)bias)[32 + l];

#pragma unroll
  for (int pass = 0; pass < 2; ++pass) {
    const int i = hw0 + pass * 25000;            // exactly covers [0, NN)
    const int deg = min(cnt[i * CSTRIDE], CAP);
    const int beg = i * CAP;
    const float4 ssv = sself4[i];
    float s0 = 0.f, s1 = 0.f;
    float4 acc0 = { 0.f, 0.f, 0.f, 0.f };
    float4 acc1 = { 0.f, 0.f, 0.f, 0.f };

    for (int base = 0; base < deg; base += 32) {
      const int c32 = min(32, deg - base);
      u32 sv = slots[beg + base + min(l, c32 - 1)];   // coalesced 4B
      int colv = (int)(sv & 0xFFFFu);

      // ---- issue round-0 fb gathers FIRST ----
      int colq[8];
      u16x4 f0[8], f1[8];
#pragma unroll
      for (int q = 0; q < 8; ++q) colq[q] = __shfl(colv, q, 32);
#pragma unroll
      for (int q = 0; q < 8; ++q) {
        const u16* fp = fb + (size_t)colq[q] * HF + l * 4;
        f0[q] = *(const u16x4*)fp;
        f1[q] = *(const u16x4*)(fp + 128);
      }

      // ---- weight math (hides under the gathers) ----
      u16 ah = (u16)(sv >> 16);
      float av = __half2float(*(const __half*)&ah);
      float4 nb = sneigh4[colv];                       // 16B gather, L2-hot
      float z0 = ssv.x + nb.x, z1 = ssv.y + nb.y;
      float z2 = ssv.z + nb.z, z3 = ssv.w + nb.w;
      float w0 = __expf((z0 > 0.f ? z0 : 0.2f * z0) * av);
      float w1 = __expf((z1 > 0.f ? z1 : 0.2f * z1) * av);
      float w2 = __expf((z2 > 0.f ? z2 : 0.2f * z2) * av);
      float w3 = __expf((z3 > 0.f ? z3 : 0.2f * z3) * av);
      if (l >= c32) { w0 = 0.f; w1 = 0.f; w2 = 0.f; w3 = 0.f; }
      __half2 h01 = __floats2half2_rn(w0, w1);
      __half2 h23 = __floats2half2_rn(w2, w3);
      u32 wy = *(u32*)&h01, wz = *(u32*)&h23;

      const int c8 = (c32 + 7) & ~7;
      for (int e = 0; e < c8; e += 8) {
        float wa[8], wb[8];
#pragma unroll
        for (int q = 0; q < 8; ++q) {
          u32 y = (u32)__shfl((int)wy, e + q, 32);
          u32 z = (u32)__shfl((int)wz, e + q, 32);
          float2 fy = __half22float2(*(const __half2*)&y);
          float2 fz = __half22float2(*(const __half2*)&z);
          wa[q] = hsel ? fy.y : fy.x;
          wb[q] = hsel ? fz.y : fz.x;
        }
#pragma unroll
        for (int q = 0; q < 8; ++q) {
          s0 += wa[q];
          s1 += wb[q];
          acc0.x = fmaf(wa[q], bf2f(f0[q][0]), acc0.x);
          acc0.y = fmaf(wa[q], bf2f(f0[q][1]), acc0.y);
          acc0.z = fmaf(wa[q], bf2f(f0[q][2]), acc0.z);
          acc0.w = fmaf(wa[q], bf2f(f0[q][3]), acc0.w);
          acc1.x = fmaf(wb[q], bf2f(f1[q][0]), acc1.x);
          acc1.y = fmaf(wb[q], bf2f(f1[q][1]), acc1.y);
          acc1.z = fmaf(wb[q], bf2f(f1[q][2]), acc1.z);
          acc1.w = fmaf(wb[q], bf2f(f1[q][3]), acc1.w);
        }
        if (e + 8 < c8) {
#pragma unroll
          for (int q = 0; q < 8; ++q) colq[q] = __shfl(colv, e + 8 + q, 32);
#pragma unroll
          for (int q = 0; q < 8; ++q) {
            const u16* fp = fb + (size_t)colq[q] * HF + l * 4;
            f0[q] = *(const u16x4*)fp;
            f1[q] = *(const u16x4*)(fp + 128);
          }
        }
      }
    }
    const float rs0 = (s0 > 0.f) ? __frcp_rn(s0) : 0.f;
    const float rs1 = (s1 > 0.f) ? __frcp_rn(s1) : 0.f;
    float4 o0, o1;
    o0.x = fmaxf(fmaf(acc0.x, rs0, b0.x), 0.f);
    o0.y = fmaxf(fmaf(acc0.y, rs0, b0.y), 0.f);
    o0.z = fmaxf(fmaf(acc0.z, rs0, b0.z), 0.f);
    o0.w = fmaxf(fmaf(acc0.w, rs0, b0.w), 0.f);
    o1.x = fmaxf(fmaf(acc1.x, rs1, b1.x), 0.f);
    o1.y = fmaxf(fmaf(acc1.y, rs1, b1.y), 0.f);
    o1.z = fmaxf(fmaf(acc1.z, rs1, b1.z), 0.f);
    o1.w = fmaxf(fmaf(acc1.w, rs1, b1.w), 0.f);
    ((float4*)out)[(size_t)i * 64 + l] = o0;
    ((float4*)out)[(size_t)i * 64 + 32 + l] = o1;
  }
}

// ---------------- launch -----------------------------------------------------
extern "C" void kernel_launch(void* const* d_in, const int* in_sizes, int n_in,
                              void* d_out, int out_size, void* d_ws, size_t ws_size,
                              hipStream_t stream) {
  const float* x       = (const float*)d_in[0];
  const float* W       = (const float*)d_in[1];
  const float* a_self  = (const float*)d_in[2];
  const float* a_neigh = (const float*)d_in[3];
  const float* bias    = (const float*)d_in[4];
  const float* adj     = (const float*)d_in[5];
  const int*   erow    = (const int*)d_in[6];
  const int*   ecol    = (const int*)d_in[7];
  float* out = (float*)d_out;

  char* w = (char*)d_ws;
  u16*   Bt     = (u16*)w;   w += 131072;             // [256][256] bf16
  u16*   fb     = (u16*)w;   w += 25600000;           // feats bf16 [NN][256]
  float* sself  = (float*)w; w += 800000;             // [NN*4]
  float* sneigh = (float*)w; w += 800000;             // [NN*4]
  int*   cnt    = (int*)w;   w += NN * CSTRIDE * 4;   // 3.2 MB padded counters
  u32*   slots  = (u32*)w;   w += NN * CAP * 4;       // 12.8 MB {col|adj_f16}

  tiny_pre_k<<<dim3(BT_B + ZERO_B), dim3(256), 0, stream>>>(W, Bt, cnt);
  gemm_scat_k<<<dim3(GEMM_B + SCAT_B), dim3(512), 0, stream>>>(
      x, Bt, fb, a_self, a_neigh, sself, sneigh,
      erow, ecol, adj, cnt, slots, NN);
  node8_k<<<dim3(NODE_B), dim3(256), 0, stream>>>(cnt, slots,
                                                  (const float4*)sself,
                                                  (const float4*)sneigh,
                                                  fb, bias, out);
}

// Round 11
// 121.434 us; speedup vs baseline: 1.1416x; 1.1416x over previous
//
#include <hip/hip_runtime.h>
#include <hip/hip_fp16.h>
#include <math.h>

#define NN 50000
#define NE 800000
#define FIN 256
#define FOUT 64
#define HEADS 4
#define HF 256    // HEADS*FOUT
#define CAP 64    // padded slots per node; P(deg>64 | Poisson(16)) ~ 1e-19/node
#define NBUCK 391 // coarse buckets (128 rows each)
#define BROWS 128
#define CAPB 4096 // per-bucket capacity; mean 2048, sigma~45 -> +45 sigma

typedef unsigned short u16;
typedef unsigned int u32;
typedef unsigned long long u64;
typedef __attribute__((ext_vector_type(4))) u16 u16x4;
typedef __attribute__((ext_vector_type(8))) u16 u16x8;
typedef __attribute__((ext_vector_type(8))) short short8;
typedef __attribute__((ext_vector_type(4))) float f32x4;

__device__ __forceinline__ u16 f2bf(float x) {
  u32 u = __float_as_uint(x);
  u += 0x7fffu + ((u >> 16) & 1u);          // RNE
  return (u16)(u >> 16);
}
__device__ __forceinline__ float bf2f(u16 u) {
  return __uint_as_float(((u32)u) << 16);
}
__device__ __forceinline__ void gload_lds16(u16* lds, const u16* g) {
  __builtin_amdgcn_global_load_lds(
      (const __attribute__((address_space(1))) u32*)g,
      (__attribute__((address_space(3))) u32*)lds, 16, 0, 0);
}

// ---------------- K0: tiny pre: make Bt + zero cntA -------------------------
#define BT_B 256
__global__ __launch_bounds__(256) void tiny_pre_k(const float* __restrict__ W,
                                                  u16* __restrict__ Bt,
                                                  int* __restrict__ cntA) {
  const int b = blockIdx.x, tid = threadIdx.x;
  if (b < BT_B) {
    int t = b * 256 + tid;                   // 65536 exactly
    int ho = t >> 8, f = t & 255;
    int h = ho >> 6, o = ho & 63;
    Bt[t] = f2bf(W[h * (FIN * FOUT) + f * FOUT + o]);
  } else {
    for (int i = tid; i < NBUCK * 16; i += 256) cntA[i] = 0;
  }
}

// ---------------- K1: 128x256-tile bf16 MFMA GEMM + fused logits ------------
__global__ __launch_bounds__(512) void gemm_lg_k(const float* __restrict__ X,
                                                 const u16* __restrict__ Bt,
                                                 u16* __restrict__ C,
                                                 const float* __restrict__ a_self,
                                                 const float* __restrict__ a_neigh,
                                                 float* __restrict__ sself,
                                                 float* __restrict__ sneigh,
                                                 int M) {
  __shared__ __align__(16) u16 smA[128 * 64];
  __shared__ __align__(16) u16 smB[256 * 64];
  const int tid = threadIdx.x;
  const int m0 = blockIdx.x * 128;
  const int lane = tid & 63, wid = tid >> 6;
  const int wr = wid >> 2, wc = wid & 3;
  const int arow = tid >> 3;                  // 0..63
  const int acol = (tid & 7) * 8;             // 0..56 step 8
  f32x4 acc[4][4] = {};

  for (int k0 = 0; k0 < FIN; k0 += 64) {
    float4 p[2][2];
#pragma unroll
    for (int c = 0; c < 2; ++c) {
      int row = m0 + c * 64 + arow;
      if (row > M - 1) row = M - 1;
      const float* ap = X + (size_t)row * 256 + k0 + acol;
      p[c][0] = *(const float4*)ap;
      p[c][1] = *(const float4*)(ap + 4);
    }
#pragma unroll
    for (int c = 0; c < 4; ++c) {
      int row = c * 64 + arow;
      gload_lds16(&smB[(c * 64 + arow) * 64 + acol], Bt + row * 256 + k0 + acol);
    }
#pragma unroll
    for (int c = 0; c < 2; ++c) {
      u16x8 av = { f2bf(p[c][0].x), f2bf(p[c][0].y), f2bf(p[c][0].z), f2bf(p[c][0].w),
                   f2bf(p[c][1].x), f2bf(p[c][1].y), f2bf(p[c][1].z), f2bf(p[c][1].w) };
      *(u16x8*)&smA[(c * 64 + arow) * 64 + acol] = av;
    }
    asm volatile("s_waitcnt vmcnt(0)" ::: "memory");
    __syncthreads();
#pragma unroll
    for (int kk = 0; kk < 2; ++kk) {
      const int kb = kk * 32 + (lane >> 4) * 8;
      short8 aF[4], bF[4];
#pragma unroll
      for (int mi = 0; mi < 4; ++mi)
        aF[mi] = *(const short8*)&smA[(wr * 64 + mi * 16 + (lane & 15)) * 64 + kb];
#pragma unroll
      for (int ni = 0; ni < 4; ++ni)
        bF[ni] = *(const short8*)&smB[(wc * 64 + ni * 16 + (lane & 15)) * 64 + kb];
#pragma unroll
      for (int mi = 0; mi < 4; ++mi)
#pragma unroll
        for (int ni = 0; ni < 4; ++ni)
          acc[mi][ni] = __builtin_amdgcn_mfma_f32_16x16x32_bf16(aF[mi], bF[ni], acc[mi][ni], 0, 0, 0);
    }
    __syncthreads();
  }
#pragma unroll
  for (int mi = 0; mi < 4; ++mi) {
#pragma unroll
    for (int ni = 0; ni < 4; ++ni) {
      f32x4 a = acc[mi][ni];
      int col = wc * 64 + ni * 16 + (lane & 15);
#pragma unroll
      for (int r = 0; r < 4; ++r) {
        int row = m0 + wr * 64 + mi * 16 + (lane >> 4) * 4 + r;
        if (row < M) C[(size_t)row * 256 + col] = f2bf(a[r]);
      }
    }
  }
  float asv[4], anv[4];
#pragma unroll
  for (int ni = 0; ni < 4; ++ni) {
    int col = wc * 64 + ni * 16 + (lane & 15);
    asv[ni] = a_self[col];
    anv[ni] = a_neigh[col];
  }
#pragma unroll
  for (int mi = 0; mi < 4; ++mi) {
#pragma unroll
    for (int r = 0; r < 4; ++r) {
      float ds = 0.f, dn = 0.f;
#pragma unroll
      for (int ni = 0; ni < 4; ++ni) {
        float v = acc[mi][ni][r];
        ds = fmaf(v, asv[ni], ds);
        dn = fmaf(v, anv[ni], dn);
      }
#pragma unroll
      for (int off = 1; off < 16; off <<= 1) {
        ds += __shfl_xor(ds, off, 64);
        dn += __shfl_xor(dn, off, 64);
      }
      if ((lane & 15) == 0) {
        int row = m0 + wr * 64 + mi * 16 + (lane >> 4) * 4 + r;
        if (row < M) {
          sself[row * 4 + wc] = ds;
          sneigh[row * 4 + wc] = dn;
        }
      }
    }
  }
}

// ---------------- K2a: coarse bin (row>>7) with LDS histogram ---------------
// 391 blocks x 512 thr x 4 edges. Semi-coalesced 8B record writes.
__global__ __launch_bounds__(512) void binA_k(const int* __restrict__ erow,
                                              const int* __restrict__ ecol,
                                              const float* __restrict__ adj,
                                              int* __restrict__ cntA,     // [NBUCK*16]
                                              u64* __restrict__ coarse) { // [NBUCK*CAPB]
  __shared__ int hist[NBUCK];
  __shared__ int gbase[NBUCK];
  const int tid = threadIdx.x;
  for (int i = tid; i < NBUCK; i += 512) hist[i] = 0;
  __syncthreads();
  const int e0 = blockIdx.x * 2048 + tid;
  int bk[4], lr[4], rl[4], ok[4];
  u32 rec[4];
#pragma unroll
  for (int j = 0; j < 4; ++j) {
    int e = e0 + j * 512;
    ok[j] = (e < NE);
    int ee = ok[j] ? e : 0;
    int r = erow[ee];
    int c = ecol[ee];
    float av = adj[ee];
    __half ha = __float2half_rn(av);
    bk[j] = r >> 7;
    rl[j] = r & 127;
    rec[j] = (u32)c | ((u32)(*(u16*)&ha) << 16);
    lr[j] = ok[j] ? atomicAdd(&hist[bk[j]], 1) : 0;
  }
  __syncthreads();
  for (int i = tid; i < NBUCK; i += 512) {
    int h = hist[i];
    gbase[i] = h ? atomicAdd(&cntA[i * 16], h) : 0;
  }
  __syncthreads();
#pragma unroll
  for (int j = 0; j < 4; ++j) {
    if (ok[j]) {
      int pos = gbase[bk[j]] + lr[j];
      if (pos < CAPB) {
        u64 v = ((u64)rl[j] << 32) | (u64)rec[j];
        coarse[(size_t)bk[j] * CAPB + pos] = v;
      }
    }
  }
}

// ---------------- K2b: fine scatter within bucket (L2-local) ----------------
// one block per bucket; LDS ranking; random 4B writes confined to 32KB.
__global__ __launch_bounds__(256) void binB_k(const int* __restrict__ cntA,
                                              const u64* __restrict__ coarse,
                                              int* __restrict__ cnt,
                                              u32* __restrict__ slots) {
  __shared__ int lcnt[BROWS];
  const int b = blockIdx.x, tid = threadIdx.x;
  for (int i = tid; i < BROWS; i += 256) lcnt[i] = 0;
  __syncthreads();
  const int n = min(cntA[b * 16], CAPB);
  const u64* src = coarse + (size_t)b * CAPB;
  for (int i = tid; i < n; i += 256) {
    u64 v = src[i];
    int rl = (int)(v >> 32);
    u32 rec = (u32)v;
    int p = atomicAdd(&lcnt[rl], 1);
    if (p < CAP) slots[((size_t)(b * BROWS + rl)) * CAP + p] = rec;
  }
  __syncthreads();
  for (int i = tid; i < BROWS; i += 256) {
    int row = b * BROWS + i;
    if (row < NN) cnt[row] = min(lcnt[i], CAP);
  }
}

// ---------------- K3: per-node weights + aggregate + bias + relu ------------
#define NODE_B 3125   // 3125 blocks x 8 half-waves = 25000; x2 nodes = NN
__global__ __launch_bounds__(256) void node8_k(const int* __restrict__ cnt,
                                               const u32* __restrict__ slots,
                                               const float4* __restrict__ sself4,
                                               const float4* __restrict__ sneigh4,
                                               const u16* __restrict__ fb,
                                               const float* __restrict__ bias,
                                               float* __restrict__ out) {
  const int tid = threadIdx.x;
  const int l = tid & 31;
  const int hsel = l >> 4;
  const int hw0 = blockIdx.x * 8 + (tid >> 5);   // 0..24999
  const float4 b0 = ((const float4*)bias)[l];
  const float4 b1 = ((const float4*)bias)[32 + l];

#pragma unroll
  for (int pass = 0; pass < 2; ++pass) {
    const int i = hw0 + pass * 25000;            // exactly covers [0, NN)
    const int deg = cnt[i];
    const int beg = i * CAP;
    const float4 ssv = sself4[i];
    float s0 = 0.f, s1 = 0.f;
    float4 acc0 = { 0.f, 0.f, 0.f, 0.f };
    float4 acc1 = { 0.f, 0.f, 0.f, 0.f };

    for (int base = 0; base < deg; base += 32) {
      const int c32 = min(32, deg - base);
      u32 sv = slots[beg + base + min(l, c32 - 1)];   // coalesced 4B
      int colv = (int)(sv & 0xFFFFu);

      // ---- issue round-0 fb gathers FIRST ----
      int colq[8];
      u16x4 f0[8], f1[8];
#pragma unroll
      for (int q = 0; q < 8; ++q) colq[q] = __shfl(colv, q, 32);
#pragma unroll
      for (int q = 0; q < 8; ++q) {
        const u16* fp = fb + (size_t)colq[q] * HF + l * 4;
        f0[q] = *(const u16x4*)fp;
        f1[q] = *(const u16x4*)(fp + 128);
      }

      // ---- weight math (hides under the gathers) ----
      u16 ah = (u16)(sv >> 16);
      float av = __half2float(*(const __half*)&ah);
      float4 nb = sneigh4[colv];                       // 16B gather, L2-hot
      float z0 = ssv.x + nb.x, z1 = ssv.y + nb.y;
      float z2 = ssv.z + nb.z, z3 = ssv.w + nb.w;
      float w0 = __expf((z0 > 0.f ? z0 : 0.2f * z0) * av);
      float w1 = __expf((z1 > 0.f ? z1 : 0.2f * z1) * av);
      float w2 = __expf((z2 > 0.f ? z2 : 0.2f * z2) * av);
      float w3 = __expf((z3 > 0.f ? z3 : 0.2f * z3) * av);
      if (l >= c32) { w0 = 0.f; w1 = 0.f; w2 = 0.f; w3 = 0.f; }
      __half2 h01 = __floats2half2_rn(w0, w1);
      __half2 h23 = __floats2half2_rn(w2, w3);
      u32 wy = *(u32*)&h01, wz = *(u32*)&h23;

      const int c8 = (c32 + 7) & ~7;
      for (int e = 0; e < c8; e += 8) {
        float wa[8], wb[8];
#pragma unroll
        for (int q = 0; q < 8; ++q) {
          u32 y = (u32)__shfl((int)wy, e + q, 32);
          u32 z = (u32)__shfl((int)wz, e + q, 32);
          float2 fy = __half22float2(*(const __half2*)&y);
          float2 fz = __half22float2(*(const __half2*)&z);
          wa[q] = hsel ? fy.y : fy.x;
          wb[q] = hsel ? fz.y : fz.x;
        }
#pragma unroll
        for (int q = 0; q < 8; ++q) {
          s0 += wa[q];
          s1 += wb[q];
          acc0.x = fmaf(wa[q], bf2f(f0[q][0]), acc0.x);
          acc0.y = fmaf(wa[q], bf2f(f0[q][1]), acc0.y);
          acc0.z = fmaf(wa[q], bf2f(f0[q][2]), acc0.z);
          acc0.w = fmaf(wa[q], bf2f(f0[q][3]), acc0.w);
          acc1.x = fmaf(wb[q], bf2f(f1[q][0]), acc1.x);
          acc1.y = fmaf(wb[q], bf2f(f1[q][1]), acc1.y);
          acc1.z = fmaf(wb[q], bf2f(f1[q][2]), acc1.z);
          acc1.w = fmaf(wb[q], bf2f(f1[q][3]), acc1.w);
        }
        if (e + 8 < c8) {
#pragma unroll
          for (int q = 0; q < 8; ++q) colq[q] = __shfl(colv, e + 8 + q, 32);
#pragma unroll
          for (int q = 0; q < 8; ++q) {
            const u16* fp = fb + (size_t)colq[q] * HF + l * 4;
            f0[q] = *(const u16x4*)fp;
            f1[q] = *(const u16x4*)(fp + 128);
          }
        }
      }
    }
    const float rs0 = (s0 > 0.f) ? __frcp_rn(s0) : 0.f;
    const float rs1 = (s1 > 0.f) ? __frcp_rn(s1) : 0.f;
    float4 o0, o1;
    o0.x = fmaxf(fmaf(acc0.x, rs0, b0.x), 0.f);
    o0.y = fmaxf(fmaf(acc0.y, rs0, b0.y), 0.f);
    o0.z = fmaxf(fmaf(acc0.z, rs0, b0.z), 0.f);
    o0.w = fmaxf(fmaf(acc0.w, rs0, b0.w), 0.f);
    o1.x = fmaxf(fmaf(acc1.x, rs1, b1.x), 0.f);
    o1.y = fmaxf(fmaf(acc1.y, rs1, b1.y), 0.f);
    o1.z = fmaxf(fmaf(acc1.z, rs1, b1.z), 0.f);
    o1.w = fmaxf(fmaf(acc1.w, rs1, b1.w), 0.f);
    ((float4*)out)[(size_t)i * 64 + l] = o0;
    ((float4*)out)[(size_t)i * 64 + 32 + l] = o1;
  }
}

// ---------------- launch -----------------------------------------------------
extern "C" void kernel_launch(void* const* d_in, const int* in_sizes, int n_in,
                              void* d_out, int out_size, void* d_ws, size_t ws_size,
                              hipStream_t stream) {
  const float* x       = (const float*)d_in[0];
  const float* W       = (const float*)d_in[1];
  const float* a_self  = (const float*)d_in[2];
  const float* a_neigh = (const float*)d_in[3];
  const float* bias    = (const float*)d_in[4];
  const float* adj     = (const float*)d_in[5];
  const int*   erow    = (const int*)d_in[6];
  const int*   ecol    = (const int*)d_in[7];
  float* out = (float*)d_out;

  char* w = (char*)d_ws;
  u16*   Bt     = (u16*)w;   w += 131072;             // [256][256] bf16
  u16*   fb     = (u16*)w;   w += 25600000;           // feats bf16 [NN][256]
  float* sself  = (float*)w; w += 800000;             // [NN*4]
  float* sneigh = (float*)w; w += 800000;             // [NN*4]
  int*   cntA   = (int*)w;   w += NBUCK * 16 * 4;     // padded bucket counters
  int*   cnt    = (int*)w;   w += 200192;             // [NN]
  u32*   slots  = (u32*)w;   w += NN * CAP * 4;       // 12.8 MB {col|adj_f16}
  u64*   coarse = (u64*)w;   w += (size_t)NBUCK * CAPB * 8;  // 12.8 MB

  tiny_pre_k<<<dim3(BT_B + 1), dim3(256), 0, stream>>>(W, Bt, cntA);
  binA_k<<<dim3(NBUCK), dim3(512), 0, stream>>>(erow, ecol, adj, cntA, coarse);
  binB_k<<<dim3(NBUCK), dim3(256), 0, stream>>>(cntA, coarse, cnt, slots);
  gemm_lg_k<<<dim3((NN + 127) / 128), dim3(512), 0, stream>>>(x, Bt, fb, a_self, a_neigh,
                                                              sself, sneigh, NN);
  node8_k<<<dim3(NODE_B), dim3(256), 0, stream>>>(cnt, slots,
                                                  (const float4*)sself,
                                                  (const float4*)sneigh,
                                                  fb, bias, out);
}

// Round 12
// 119.369 us; speedup vs baseline: 1.1613x; 1.0173x over previous
//
#include <hip/hip_runtime.h>
#include <hip/hip_fp16.h>
#include <math.h>

#define NN 50000
#define NE 800000
#define FIN 256
#define FOUT 64
#define HEADS 4
#define HF 256    // HEADS*FOUT
#define CAP 64    // padded slots per node; P(deg>64 | Poisson(16)) ~ 1e-19/node
#define NBUCK 391 // coarse buckets (128 rows each)
#define BROWS 128
#define CAPB 4096 // per-bucket capacity; mean 2048

typedef unsigned short u16;
typedef unsigned int u32;
typedef unsigned long long u64;
typedef __attribute__((ext_vector_type(4))) u16 u16x4;
typedef __attribute__((ext_vector_type(8))) u16 u16x8;
typedef __attribute__((ext_vector_type(8))) short short8;
typedef __attribute__((ext_vector_type(4))) float f32x4;

__device__ __forceinline__ u16 f2bf(float x) {
  u32 u = __float_as_uint(x);
  u += 0x7fffu + ((u >> 16) & 1u);          // RNE
  return (u16)(u >> 16);
}
__device__ __forceinline__ float bf2f(u16 u) {
  return __uint_as_float(((u32)u) << 16);
}
__device__ __forceinline__ void gload_lds16(u16* lds, const u16* g) {
  __builtin_amdgcn_global_load_lds(
      (const __attribute__((address_space(1))) u32*)g,
      (__attribute__((address_space(3))) u32*)lds, 16, 0, 0);
}

// ---------------- K0: tiny pre: make Bt + zero cntA -------------------------
#define BT_B 256
__global__ __launch_bounds__(256) void tiny_pre_k(const float* __restrict__ W,
                                                  u16* __restrict__ Bt,
                                                  int* __restrict__ cntA) {
  const int b = blockIdx.x, tid = threadIdx.x;
  if (b < BT_B) {
    int t = b * 256 + tid;                   // 65536 exactly
    int ho = t >> 8, f = t & 255;
    int h = ho >> 6, o = ho & 63;
    Bt[t] = f2bf(W[h * (FIN * FOUT) + f * FOUT + o]);
  } else {
    for (int i = tid; i < NBUCK * 16; i += 256) cntA[i] = 0;
  }
}

// ---------------- K1: FUSED  binA (blocks 0..390)  ||  GEMM (391..781) ------
// binA: coarse bin (row>>7), LDS histogram, semi-coalesced 8B writes.
// GEMM: 128x256 bf16 MFMA + fused per-row logits. Disjoint data -> overlap.
__global__ __launch_bounds__(512) void fused_k(const float* __restrict__ X,
                                               const u16* __restrict__ Bt,
                                               u16* __restrict__ C,
                                               const float* __restrict__ a_self,
                                               const float* __restrict__ a_neigh,
                                               float* __restrict__ sself,
                                               float* __restrict__ sneigh,
                                               const int* __restrict__ erow,
                                               const int* __restrict__ ecol,
                                               const float* __restrict__ adj,
                                               int* __restrict__ cntA,
                                               u64* __restrict__ coarse,
                                               int M) {
  __shared__ __align__(16) u16 smA[128 * 64];
  __shared__ __align__(16) u16 smB[256 * 64];
  __shared__ int hist[NBUCK];
  __shared__ int gbase[NBUCK];
  const int tid = threadIdx.x;

  if (blockIdx.x < NBUCK) {
    // ---------------- binA part ----------------
    for (int i = tid; i < NBUCK; i += 512) hist[i] = 0;
    __syncthreads();
    const int e0 = blockIdx.x * 2048 + tid;
    int bk[4], lr[4], rl[4], ok[4];
    u32 rec[4];
#pragma unroll
    for (int j = 0; j < 4; ++j) {
      int e = e0 + j * 512;
      ok[j] = (e < NE);
      int ee = ok[j] ? e : 0;
      int r = erow[ee];
      int c = ecol[ee];
      float av = adj[ee];
      __half ha = __float2half_rn(av);
      bk[j] = r >> 7;
      rl[j] = r & 127;
      rec[j] = (u32)c | ((u32)(*(u16*)&ha) << 16);
      lr[j] = ok[j] ? atomicAdd(&hist[bk[j]], 1) : 0;
    }
    __syncthreads();
    for (int i = tid; i < NBUCK; i += 512) {
      int h = hist[i];
      gbase[i] = h ? atomicAdd(&cntA[i * 16], h) : 0;
    }
    __syncthreads();
#pragma unroll
    for (int j = 0; j < 4; ++j) {
      if (ok[j]) {
        int pos = gbase[bk[j]] + lr[j];
        if (pos < CAPB) {
          u64 v = ((u64)rl[j] << 32) | (u64)rec[j];
          coarse[(size_t)bk[j] * CAPB + pos] = v;
        }
      }
    }
    return;
  }

  // ---------------- gemm part ----------------
  const int m0 = (blockIdx.x - NBUCK) * 128;
  const int lane = tid & 63, wid = tid >> 6;
  const int wr = wid >> 2, wc = wid & 3;
  const int arow = tid >> 3;                  // 0..63
  const int acol = (tid & 7) * 8;             // 0..56 step 8
  f32x4 acc[4][4] = {};

  for (int k0 = 0; k0 < FIN; k0 += 64) {
    float4 p[2][2];
#pragma unroll
    for (int c = 0; c < 2; ++c) {
      int row = m0 + c * 64 + arow;
      if (row > M - 1) row = M - 1;
      const float* ap = X + (size_t)row * 256 + k0 + acol;
      p[c][0] = *(const float4*)ap;
      p[c][1] = *(const float4*)(ap + 4);
    }
#pragma unroll
    for (int c = 0; c < 4; ++c) {
      int row = c * 64 + arow;
      gload_lds16(&smB[(c * 64 + arow) * 64 + acol], Bt + row * 256 + k0 + acol);
    }
#pragma unroll
    for (int c = 0; c < 2; ++c) {
      u16x8 av = { f2bf(p[c][0].x), f2bf(p[c][0].y), f2bf(p[c][0].z), f2bf(p[c][0].w),
                   f2bf(p[c][1].x), f2bf(p[c][1].y), f2bf(p[c][1].z), f2bf(p[c][1].w) };
      *(u16x8*)&smA[(c * 64 + arow) * 64 + acol] = av;
    }
    asm volatile("s_waitcnt vmcnt(0)" ::: "memory");
    __syncthreads();
#pragma unroll
    for (int kk = 0; kk < 2; ++kk) {
      const int kb = kk * 32 + (lane >> 4) * 8;
      short8 aF[4], bF[4];
#pragma unroll
      for (int mi = 0; mi < 4; ++mi)
        aF[mi] = *(const short8*)&smA[(wr * 64 + mi * 16 + (lane & 15)) * 64 + kb];
#pragma unroll
      for (int ni = 0; ni < 4; ++ni)
        bF[ni] = *(const short8*)&smB[(wc * 64 + ni * 16 + (lane & 15)) * 64 + kb];
#pragma unroll
      for (int mi = 0; mi < 4; ++mi)
#pragma unroll
        for (int ni = 0; ni < 4; ++ni)
          acc[mi][ni] = __builtin_amdgcn_mfma_f32_16x16x32_bf16(aF[mi], bF[ni], acc[mi][ni], 0, 0, 0);
    }
    __syncthreads();
  }
#pragma unroll
  for (int mi = 0; mi < 4; ++mi) {
#pragma unroll
    for (int ni = 0; ni < 4; ++ni) {
      f32x4 a = acc[mi][ni];
      int col = wc * 64 + ni * 16 + (lane & 15);
#pragma unroll
      for (int r = 0; r < 4; ++r) {
        int row = m0 + wr * 64 + mi * 16 + (lane >> 4) * 4 + r;
        if (row < M) C[(size_t)row * 256 + col] = f2bf(a[r]);
      }
    }
  }
  float asv[4], anv[4];
#pragma unroll
  for (int ni = 0; ni < 4; ++ni) {
    int col = wc * 64 + ni * 16 + (lane & 15);
    asv[ni] = a_self[col];
    anv[ni] = a_neigh[col];
  }
#pragma unroll
  for (int mi = 0; mi < 4; ++mi) {
#pragma unroll
    for (int r = 0; r < 4; ++r) {
      float ds = 0.f, dn = 0.f;
#pragma unroll
      for (int ni = 0; ni < 4; ++ni) {
        float v = acc[mi][ni][r];
        ds = fmaf(v, asv[ni], ds);
        dn = fmaf(v, anv[ni], dn);
      }
#pragma unroll
      for (int off = 1; off < 16; off <<= 1) {
        ds += __shfl_xor(ds, off, 64);
        dn += __shfl_xor(dn, off, 64);
      }
      if ((lane & 15) == 0) {
        int row = m0 + wr * 64 + mi * 16 + (lane >> 4) * 4 + r;
        if (row < M) {
          sself[row * 4 + wc] = ds;
          sneigh[row * 4 + wc] = dn;
        }
      }
    }
  }
}

// ---------------- K2: fine scatter within bucket (L2-local) -----------------
__global__ __launch_bounds__(256) void binB_k(const int* __restrict__ cntA,
                                              const u64* __restrict__ coarse,
                                              int* __restrict__ cnt,
                                              u32* __restrict__ slots) {
  __shared__ int lcnt[BROWS];
  const int b = blockIdx.x, tid = threadIdx.x;
  for (int i = tid; i < BROWS; i += 256) lcnt[i] = 0;
  __syncthreads();
  const int n = min(cntA[b * 16], CAPB);
  const u64* src = coarse + (size_t)b * CAPB;
  for (int i = tid; i < n; i += 256) {
    u64 v = src[i];
    int rl = (int)(v >> 32);
    u32 rec = (u32)v;
    int p = atomicAdd(&lcnt[rl], 1);
    if (p < CAP) slots[((size_t)(b * BROWS + rl)) * CAP + p] = rec;
  }
  __syncthreads();
  for (int i = tid; i < BROWS; i += 256) {
    int row = b * BROWS + i;
    if (row < NN) cnt[row] = min(lcnt[i], CAP);
  }
}

// ---------------- K3: per-node weights + aggregate + bias + relu ------------
#define NODE_B 3125   // 3125 blocks x 8 half-waves = 25000; x2 nodes = NN
__global__ __launch_bounds__(256) void node8_k(const int* __restrict__ cnt,
                                               const u32* __restrict__ slots,
                                               const float4* __restrict__ sself4,
                                               const float4* __restrict__ sneigh4,
                                               const u16* __restrict__ fb,
                                               const float* __restrict__ bias,
                                               float* __restrict__ out) {
  const int tid = threadIdx.x;
  const int l = tid & 31;
  const int hsel = l >> 4;
  const int hw0 = blockIdx.x * 8 + (tid >> 5);   // 0..24999
  const float4 b0 = ((const float4*)bias)[l];
  const float4 b1 = ((const float4*)bias)[32 + l];

#pragma unroll
  for (int pass = 0; pass < 2; ++pass) {
    const int i = hw0 + pass * 25000;            // exactly covers [0, NN)
    const int deg = cnt[i];
    const int beg = i * CAP;
    const float4 ssv = sself4[i];
    float s0 = 0.f, s1 = 0.f;
    float4 acc0 = { 0.f, 0.f, 0.f, 0.f };
    float4 acc1 = { 0.f, 0.f, 0.f, 0.f };

    for (int base = 0; base < deg; base += 32) {
      const int c32 = min(32, deg - base);
      u32 sv = slots[beg + base + min(l, c32 - 1)];   // coalesced 4B
      int colv = (int)(sv & 0xFFFFu);

      int colq[8];
      u16x4 f0[8], f1[8];
#pragma unroll
      for (int q = 0; q < 8; ++q) colq[q] = __shfl(colv, q, 32);
#pragma unroll
      for (int q = 0; q < 8; ++q) {
        const u16* fp = fb + (size_t)colq[q] * HF + l * 4;
        f0[q] = *(const u16x4*)fp;
        f1[q] = *(const u16x4*)(fp + 128);
      }

      u16 ah = (u16)(sv >> 16);
      float av = __half2float(*(const __half*)&ah);
      float4 nb = sneigh4[colv];
      float z0 = ssv.x + nb.x, z1 = ssv.y + nb.y;
      float z2 = ssv.z + nb.z, z3 = ssv.w + nb.w;
      float w0 = __expf((z0 > 0.f ? z0 : 0.2f * z0) * av);
      float w1 = __expf((z1 > 0.f ? z1 : 0.2f * z1) * av);
      float w2 = __expf((z2 > 0.f ? z2 : 0.2f * z2) * av);
      float w3 = __expf((z3 > 0.f ? z3 : 0.2f * z3) * av);
      if (l >= c32) { w0 = 0.f; w1 = 0.f; w2 = 0.f; w3 = 0.f; }
      __half2 h01 = __floats2half2_rn(w0, w1);
      __half2 h23 = __floats2half2_rn(w2, w3);
      u32 wy = *(u32*)&h01, wz = *(u32*)&h23;

      const int c8 = (c32 + 7) & ~7;
      for (int e = 0; e < c8; e += 8) {
        float wa[8], wb[8];
#pragma unroll
        for (int q = 0; q < 8; ++q) {
          u32 y = (u32)__shfl((int)wy, e + q, 32);
          u32 z = (u32)__shfl((int)wz, e + q, 32);
          float2 fy = __half22float2(*(const __half2*)&y);
          float2 fz = __half22float2(*(const __half2*)&z);
          wa[q] = hsel ? fy.y : fy.x;
          wb[q] = hsel ? fz.y : fz.x;
        }
#pragma unroll
        for (int q = 0; q < 8; ++q) {
          s0 += wa[q];
          s1 += wb[q];
          acc0.x = fmaf(wa[q], bf2f(f0[q][0]), acc0.x);
          acc0.y = fmaf(wa[q], bf2f(f0[q][1]), acc0.y);
          acc0.z = fmaf(wa[q], bf2f(f0[q][2]), acc0.z);
          acc0.w = fmaf(wa[q], bf2f(f0[q][3]), acc0.w);
          acc1.x = fmaf(wb[q], bf2f(f1[q][0]), acc1.x);
          acc1.y = fmaf(wb[q], bf2f(f1[q][1]), acc1.y);
          acc1.z = fmaf(wb[q], bf2f(f1[q][2]), acc1.z);
          acc1.w = fmaf(wb[q], bf2f(f1[q][3]), acc1.w);
        }
        if (e + 8 < c8) {
#pragma unroll
          for (int q = 0; q < 8; ++q) colq[q] = __shfl(colv, e + 8 + q, 32);
#pragma unroll
          for (int q = 0; q < 8; ++q) {
            const u16* fp = fb + (size_t)colq[q] * HF + l * 4;
            f0[q] = *(const u16x4*)fp;
            f1[q] = *(const u16x4*)(fp + 128);
          }
        }
      }
    }
    const float rs0 = (s0 > 0.f) ? __frcp_rn(s0) : 0.f;
    const float rs1 = (s1 > 0.f) ? __frcp_rn(s1) : 0.f;
    float4 o0, o1;
    o0.x = fmaxf(fmaf(acc0.x, rs0, b0.x), 0.f);
    o0.y = fmaxf(fmaf(acc0.y, rs0, b0.y), 0.f);
    o0.z = fmaxf(fmaf(acc0.z, rs0, b0.z), 0.f);
    o0.w = fmaxf(fmaf(acc0.w, rs0, b0.w), 0.f);
    o1.x = fmaxf(fmaf(acc1.x, rs1, b1.x), 0.f);
    o1.y = fmaxf(fmaf(acc1.y, rs1, b1.y), 0.f);
    o1.z = fmaxf(fmaf(acc1.z, rs1, b1.z), 0.f);
    o1.w = fmaxf(fmaf(acc1.w, rs1, b1.w), 0.f);
    ((float4*)out)[(size_t)i * 64 + l] = o0;
    ((float4*)out)[(size_t)i * 64 + 32 + l] = o1;
  }
}

// ---------------- launch -----------------------------------------------------
extern "C" void kernel_launch(void* const* d_in, const int* in_sizes, int n_in,
                              void* d_out, int out_size, void* d_ws, size_t ws_size,
                              hipStream_t stream) {
  const float* x       = (const float*)d_in[0];
  const float* W       = (const float*)d_in[1];
  const float* a_self  = (const float*)d_in[2];
  const float* a_neigh = (const float*)d_in[3];
  const float* bias    = (const float*)d_in[4];
  const float* adj     = (const float*)d_in[5];
  const int*   erow    = (const int*)d_in[6];
  const int*   ecol    = (const int*)d_in[7];
  float* out = (float*)d_out;

  char* w = (char*)d_ws;
  u16*   Bt     = (u16*)w;   w += 131072;             // [256][256] bf16
  u16*   fb     = (u16*)w;   w += 25600000;           // feats bf16 [NN][256]
  float* sself  = (float*)w; w += 800000;             // [NN*4]
  float* sneigh = (float*)w; w += 800000;             // [NN*4]
  int*   cntA   = (int*)w;   w += NBUCK * 16 * 4;     // padded bucket counters
  int*   cnt    = (int*)w;   w += 200192;             // [NN]
  u32*   slots  = (u32*)w;   w += NN * CAP * 4;       // 12.8 MB {col|adj_f16}
  u64*   coarse = (u64*)w;   w += (size_t)NBUCK * CAPB * 8;  // 12.8 MB

  tiny_pre_k<<<dim3(BT_B + 1), dim3(256), 0, stream>>>(W, Bt, cntA);
  fused_k<<<dim3(NBUCK + (NN + 127) / 128), dim3(512), 0, stream>>>(
      x, Bt, fb, a_self, a_neigh, sself, sneigh,
      erow, ecol, adj, cntA, coarse, NN);
  binB_k<<<dim3(NBUCK), dim3(256), 0, stream>>>(cntA, coarse, cnt, slots);
  node8_k<<<dim3(NODE_B), dim3(256), 0, stream>>>(cnt, slots,
                                                  (const float4*)sself,
                                                  (const float4*)sneigh,
                                                  fb, bias, out);
}

// Round 13
// 114.227 us; speedup vs baseline: 1.2136x; 1.0450x over previous
//
#include <hip/hip_runtime.h>
#include <hip/hip_fp16.h>
#include <math.h>

#define NN 50000
#define NE 800000
#define FIN 256
#define FOUT 64
#define HEADS 4
#define HF 256    // HEADS*FOUT
#define CAP 64    // padded slots per node; P(deg>64 | Poisson(16)) ~ 1e-19/node
#define NBUCK 391 // coarse buckets (128 rows each)
#define BROWS 128
#define CAPB 4096 // per-bucket capacity; mean 2048
#define BT_BLOCKS 32 // 32 x 512 x 4 = 65536 Bt elements

typedef unsigned short u16;
typedef unsigned int u32;
typedef unsigned long long u64;
typedef __attribute__((ext_vector_type(4))) u16 u16x4;
typedef __attribute__((ext_vector_type(8))) u16 u16x8;
typedef __attribute__((ext_vector_type(8))) short short8;
typedef __attribute__((ext_vector_type(4))) float f32x4;

__device__ __forceinline__ u16 f2bf(float x) {
  u32 u = __float_as_uint(x);
  u += 0x7fffu + ((u >> 16) & 1u);          // RNE
  return (u16)(u >> 16);
}
__device__ __forceinline__ float bf2f(u16 u) {
  return __uint_as_float(((u32)u) << 16);
}
__device__ __forceinline__ void gload_lds16(u16* lds, const u16* g) {
  __builtin_amdgcn_global_load_lds(
      (const __attribute__((address_space(1))) u32*)g,
      (__attribute__((address_space(3))) u32*)lds, 16, 0, 0);
}

// ---------------- D1: binA (blocks 0..390, long pole)  ||  Bt build ---------
__global__ __launch_bounds__(512) void binA_bt_k(const int* __restrict__ erow,
                                                 const int* __restrict__ ecol,
                                                 const float* __restrict__ adj,
                                                 int* __restrict__ cntA,
                                                 u64* __restrict__ coarse,
                                                 const float* __restrict__ W,
                                                 u16* __restrict__ Bt) {
  __shared__ int hist[NBUCK];
  __shared__ int gbase[NBUCK];
  const int tid = threadIdx.x;

  if (blockIdx.x >= NBUCK) {
    // ---- Bt build: Bt[ho][f] = W[h][f][o], 4 consecutive f per thread ----
    int t0 = (blockIdx.x - NBUCK) * 2048 + tid * 4;  // 65536 exactly
    int ho = t0 >> 8, f0 = t0 & 255;
    int h = ho >> 6, o = ho & 63;
    const float* wp = W + h * (FIN * FOUT) + o;
    u16x4 v = { f2bf(wp[(f0 + 0) * FOUT]), f2bf(wp[(f0 + 1) * FOUT]),
                f2bf(wp[(f0 + 2) * FOUT]), f2bf(wp[(f0 + 3) * FOUT]) };
    *(u16x4*)&Bt[t0] = v;
    return;
  }

  // ---- binA: coarse bin (row>>7), LDS histogram, semi-coalesced 8B writes --
  for (int i = tid; i < NBUCK; i += 512) hist[i] = 0;
  __syncthreads();
  const int e0 = blockIdx.x * 2048 + tid;
  int bk[4], lr[4], rl[4], ok[4];
  u32 rec[4];
#pragma unroll
  for (int j = 0; j < 4; ++j) {
    int e = e0 + j * 512;
    ok[j] = (e < NE);
    int ee = ok[j] ? e : 0;
    int r = erow[ee];
    int c = ecol[ee];
    float av = adj[ee];
    __half ha = __float2half_rn(av);
    bk[j] = r >> 7;
    rl[j] = r & 127;
    rec[j] = (u32)c | ((u32)(*(u16*)&ha) << 16);
    lr[j] = ok[j] ? atomicAdd(&hist[bk[j]], 1) : 0;
  }
  __syncthreads();
  for (int i = tid; i < NBUCK; i += 512) {
    int h = hist[i];
    gbase[i] = h ? atomicAdd(&cntA[i * 16], h) : 0;
  }
  __syncthreads();
#pragma unroll
  for (int j = 0; j < 4; ++j) {
    if (ok[j]) {
      int pos = gbase[bk[j]] + lr[j];
      if (pos < CAPB) {
        u64 v = ((u64)rl[j] << 32) | (u64)rec[j];
        coarse[(size_t)bk[j] * CAPB + pos] = v;
      }
    }
  }
}

// ---------------- D2: GEMM (blocks 0..390, long pole)  ||  binB -------------
__global__ __launch_bounds__(512) void gemm_binB_k(const float* __restrict__ X,
                                                   const u16* __restrict__ Bt,
                                                   u16* __restrict__ C,
                                                   const float* __restrict__ a_self,
                                                   const float* __restrict__ a_neigh,
                                                   float* __restrict__ sself,
                                                   float* __restrict__ sneigh,
                                                   const int* __restrict__ cntA,
                                                   const u64* __restrict__ coarse,
                                                   int* __restrict__ cnt,
                                                   u32* __restrict__ slots,
                                                   int M) {
  __shared__ __align__(16) u16 smA[128 * 64];
  __shared__ __align__(16) u16 smB[256 * 64];
  __shared__ int lcnt[BROWS];
  const int tid = threadIdx.x;

  if (blockIdx.x >= NBUCK) {
    // ---- binB: fine scatter within bucket (L2-local) ----
    const int b = blockIdx.x - NBUCK;
    for (int i = tid; i < BROWS; i += 512) lcnt[i] = 0;
    __syncthreads();
    const int n = min(cntA[b * 16], CAPB);
    const u64* src = coarse + (size_t)b * CAPB;
    for (int i = tid; i < n; i += 512) {
      u64 v = src[i];
      int rl = (int)(v >> 32);
      u32 rec = (u32)v;
      int p = atomicAdd(&lcnt[rl], 1);
      if (p < CAP) slots[((size_t)(b * BROWS + rl)) * CAP + p] = rec;
    }
    __syncthreads();
    for (int i = tid; i < BROWS; i += 512) {
      int row = b * BROWS + i;
      if (row < NN) cnt[row] = min(lcnt[i], CAP);
    }
    return;
  }

  // ---- gemm: 128x256 bf16 MFMA + fused per-row logits ----
  const int m0 = blockIdx.x * 128;
  const int lane = tid & 63, wid = tid >> 6;
  const int wr = wid >> 2, wc = wid & 3;
  const int arow = tid >> 3;                  // 0..63
  const int acol = (tid & 7) * 8;             // 0..56 step 8
  f32x4 acc[4][4] = {};

  for (int k0 = 0; k0 < FIN; k0 += 64) {
    float4 p[2][2];
#pragma unroll
    for (int c = 0; c < 2; ++c) {
      int row = m0 + c * 64 + arow;
      if (row > M - 1) row = M - 1;
      const float* ap = X + (size_t)row * 256 + k0 + acol;
      p[c][0] = *(const float4*)ap;
      p[c][1] = *(const float4*)(ap + 4);
    }
#pragma unroll
    for (int c = 0; c < 4; ++c) {
      int row = c * 64 + arow;
      gload_lds16(&smB[(c * 64 + arow) * 64 + acol], Bt + row * 256 + k0 + acol);
    }
#pragma unroll
    for (int c = 0; c < 2; ++c) {
      u16x8 av = { f2bf(p[c][0].x), f2bf(p[c][0].y), f2bf(p[c][0].z), f2bf(p[c][0].w),
                   f2bf(p[c][1].x), f2bf(p[c][1].y), f2bf(p[c][1].z), f2bf(p[c][1].w) };
      *(u16x8*)&smA[(c * 64 + arow) * 64 + acol] = av;
    }
    asm volatile("s_waitcnt vmcnt(0)" ::: "memory");
    __syncthreads();
#pragma unroll
    for (int kk = 0; kk < 2; ++kk) {
      const int kb = kk * 32 + (lane >> 4) * 8;
      short8 aF[4], bF[4];
#pragma unroll
      for (int mi = 0; mi < 4; ++mi)
        aF[mi] = *(const short8*)&smA[(wr * 64 + mi * 16 + (lane & 15)) * 64 + kb];
#pragma unroll
      for (int ni = 0; ni < 4; ++ni)
        bF[ni] = *(const short8*)&smB[(wc * 64 + ni * 16 + (lane & 15)) * 64 + kb];
#pragma unroll
      for (int mi = 0; mi < 4; ++mi)
#pragma unroll
        for (int ni = 0; ni < 4; ++ni)
          acc[mi][ni] = __builtin_amdgcn_mfma_f32_16x16x32_bf16(aF[mi], bF[ni], acc[mi][ni], 0, 0, 0);
    }
    __syncthreads();
  }
#pragma unroll
  for (int mi = 0; mi < 4; ++mi) {
#pragma unroll
    for (int ni = 0; ni < 4; ++ni) {
      f32x4 a = acc[mi][ni];
      int col = wc * 64 + ni * 16 + (lane & 15);
#pragma unroll
      for (int r = 0; r < 4; ++r) {
        int row = m0 + wr * 64 + mi * 16 + (lane >> 4) * 4 + r;
        if (row < M) C[(size_t)row * 256 + col] = f2bf(a[r]);
      }
    }
  }
  float asv[4], anv[4];
#pragma unroll
  for (int ni = 0; ni < 4; ++ni) {
    int col = wc * 64 + ni * 16 + (lane & 15);
    asv[ni] = a_self[col];
    anv[ni] = a_neigh[col];
  }
#pragma unroll
  for (int mi = 0; mi < 4; ++mi) {
#pragma unroll
    for (int r = 0; r < 4; ++r) {
      float ds = 0.f, dn = 0.f;
#pragma unroll
      for (int ni = 0; ni < 4; ++ni) {
        float v = acc[mi][ni][r];
        ds = fmaf(v, asv[ni], ds);
        dn = fmaf(v, anv[ni], dn);
      }
#pragma unroll
      for (int off = 1; off < 16; off <<= 1) {
        ds += __shfl_xor(ds, off, 64);
        dn += __shfl_xor(dn, off, 64);
      }
      if ((lane & 15) == 0) {
        int row = m0 + wr * 64 + mi * 16 + (lane >> 4) * 4 + r;
        if (row < M) {
          sself[row * 4 + wc] = ds;
          sneigh[row * 4 + wc] = dn;
        }
      }
    }
  }
}

// ---------------- D3: per-node weights + aggregate + bias + relu ------------
#define NODE_B 3125   // 3125 blocks x 8 half-waves = 25000; x2 nodes = NN
__global__ __launch_bounds__(256) void node8_k(const int* __restrict__ cnt,
                                               const u32* __restrict__ slots,
                                               const float4* __restrict__ sself4,
                                               const float4* __restrict__ sneigh4,
                                               const u16* __restrict__ fb,
                                               const float* __restrict__ bias,
                                               float* __restrict__ out) {
  const int tid = threadIdx.x;
  const int l = tid & 31;
  const int hsel = l >> 4;
  const int hw0 = blockIdx.x * 8 + (tid >> 5);   // 0..24999
  const float4 b0 = ((const float4*)bias)[l];
  const float4 b1 = ((const float4*)bias)[32 + l];

#pragma unroll
  for (int pass = 0; pass < 2; ++pass) {
    const int i = hw0 + pass * 25000;            // exactly covers [0, NN)
    const int deg = cnt[i];
    const int beg = i * CAP;
    const float4 ssv = sself4[i];
    float s0 = 0.f, s1 = 0.f;
    float4 acc0 = { 0.f, 0.f, 0.f, 0.f };
    float4 acc1 = { 0.f, 0.f, 0.f, 0.f };

    for (int base = 0; base < deg; base += 32) {
      const int c32 = min(32, deg - base);
      u32 sv = slots[beg + base + min(l, c32 - 1)];   // coalesced 4B
      int colv = (int)(sv & 0xFFFFu);

      int colq[8];
      u16x4 f0[8], f1[8];
#pragma unroll
      for (int q = 0; q < 8; ++q) colq[q] = __shfl(colv, q, 32);
#pragma unroll
      for (int q = 0; q < 8; ++q) {
        const u16* fp = fb + (size_t)colq[q] * HF + l * 4;
        f0[q] = *(const u16x4*)fp;
        f1[q] = *(const u16x4*)(fp + 128);
      }

      u16 ah = (u16)(sv >> 16);
      float av = __half2float(*(const __half*)&ah);
      float4 nb = sneigh4[colv];
      float z0 = ssv.x + nb.x, z1 = ssv.y + nb.y;
      float z2 = ssv.z + nb.z, z3 = ssv.w + nb.w;
      float w0 = __expf((z0 > 0.f ? z0 : 0.2f * z0) * av);
      float w1 = __expf((z1 > 0.f ? z1 : 0.2f * z1) * av);
      float w2 = __expf((z2 > 0.f ? z2 : 0.2f * z2) * av);
      float w3 = __expf((z3 > 0.f ? z3 : 0.2f * z3) * av);
      if (l >= c32) { w0 = 0.f; w1 = 0.f; w2 = 0.f; w3 = 0.f; }
      __half2 h01 = __floats2half2_rn(w0, w1);
      __half2 h23 = __floats2half2_rn(w2, w3);
      u32 wy = *(u32*)&h01, wz = *(u32*)&h23;

      const int c8 = (c32 + 7) & ~7;
      for (int e = 0; e < c8; e += 8) {
        float wa[8], wb[8];
#pragma unroll
        for (int q = 0; q < 8; ++q) {
          u32 y = (u32)__shfl((int)wy, e + q, 32);
          u32 z = (u32)__shfl((int)wz, e + q, 32);
          float2 fy = __half22float2(*(const __half2*)&y);
          float2 fz = __half22float2(*(const __half2*)&z);
          wa[q] = hsel ? fy.y : fy.x;
          wb[q] = hsel ? fz.y : fz.x;
        }
#pragma unroll
        for (int q = 0; q < 8; ++q) {
          s0 += wa[q];
          s1 += wb[q];
          acc0.x = fmaf(wa[q], bf2f(f0[q][0]), acc0.x);
          acc0.y = fmaf(wa[q], bf2f(f0[q][1]), acc0.y);
          acc0.z = fmaf(wa[q], bf2f(f0[q][2]), acc0.z);
          acc0.w = fmaf(wa[q], bf2f(f0[q][3]), acc0.w);
          acc1.x = fmaf(wb[q], bf2f(f1[q][0]), acc1.x);
          acc1.y = fmaf(wb[q], bf2f(f1[q][1]), acc1.y);
          acc1.z = fmaf(wb[q], bf2f(f1[q][2]), acc1.z);
          acc1.w = fmaf(wb[q], bf2f(f1[q][3]), acc1.w);
        }
        if (e + 8 < c8) {
#pragma unroll
          for (int q = 0; q < 8; ++q) colq[q] = __shfl(colv, e + 8 + q, 32);
#pragma unroll
          for (int q = 0; q < 8; ++q) {
            const u16* fp = fb + (size_t)colq[q] * HF + l * 4;
            f0[q] = *(const u16x4*)fp;
            f1[q] = *(const u16x4*)(fp + 128);
          }
        }
      }
    }
    const float rs0 = (s0 > 0.f) ? __frcp_rn(s0) : 0.f;
    const float rs1 = (s1 > 0.f) ? __frcp_rn(s1) : 0.f;
    float4 o0, o1;
    o0.x = fmaxf(fmaf(acc0.x, rs0, b0.x), 0.f);
    o0.y = fmaxf(fmaf(acc0.y, rs0, b0.y), 0.f);
    o0.z = fmaxf(fmaf(acc0.z, rs0, b0.z), 0.f);
    o0.w = fmaxf(fmaf(acc0.w, rs0, b0.w), 0.f);
    o1.x = fmaxf(fmaf(acc1.x, rs1, b1.x), 0.f);
    o1.y = fmaxf(fmaf(acc1.y, rs1, b1.y), 0.f);
    o1.z = fmaxf(fmaf(acc1.z, rs1, b1.z), 0.f);
    o1.w = fmaxf(fmaf(acc1.w, rs1, b1.w), 0.f);
    ((float4*)out)[(size_t)i * 64 + l] = o0;
    ((float4*)out)[(size_t)i * 64 + 32 + l] = o1;
  }
}

// ---------------- launch -----------------------------------------------------
extern "C" void kernel_launch(void* const* d_in, const int* in_sizes, int n_in,
                              void* d_out, int out_size, void* d_ws, size_t ws_size,
                              hipStream_t stream) {
  const float* x       = (const float*)d_in[0];
  const float* W       = (const float*)d_in[1];
  const float* a_self  = (const float*)d_in[2];
  const float* a_neigh = (const float*)d_in[3];
  const float* bias    = (const float*)d_in[4];
  const float* adj     = (const float*)d_in[5];
  const int*   erow    = (const int*)d_in[6];
  const int*   ecol    = (const int*)d_in[7];
  float* out = (float*)d_out;

  char* w = (char*)d_ws;
  u16*   Bt     = (u16*)w;   w += 131072;             // [256][256] bf16
  u16*   fb     = (u16*)w;   w += 25600000;           // feats bf16 [NN][256]
  float* sself  = (float*)w; w += 800000;             // [NN*4]
  float* sneigh = (float*)w; w += 800000;             // [NN*4]
  int*   cntA   = (int*)w;   w += NBUCK * 16 * 4;     // padded bucket counters
  int*   cnt    = (int*)w;   w += 200192;             // [NN]
  u32*   slots  = (u32*)w;   w += NN * CAP * 4;       // 12.8 MB {col|adj_f16}
  u64*   coarse = (u64*)w;   w += (size_t)NBUCK * CAPB * 8;  // 12.8 MB

  hipMemsetAsync(cntA, 0, NBUCK * 16 * sizeof(int), stream);
  binA_bt_k<<<dim3(NBUCK + BT_BLOCKS), dim3(512), 0, stream>>>(erow, ecol, adj,
                                                               cntA, coarse, W, Bt);
  gemm_binB_k<<<dim3(NBUCK + NBUCK), dim3(512), 0, stream>>>(
      x, Bt, fb, a_self, a_neigh, sself, sneigh, cntA, coarse, cnt, slots, NN);
  node8_k<<<dim3(NODE_B), dim3(256), 0, stream>>>(cnt, slots,
                                                  (const float4*)sself,
                                                  (const float4*)sneigh,
                                                  fb, bias, out);
}